// Round 1
// baseline (7368.320 us; speedup 1.0000x reference)
//
#include <hip/hip_runtime.h>

#define NN 50000
#define NE 800000
#define F_IN 128
#define HID 256
#define N_CLS 64

// ---------------- degree ----------------
__global__ void deg_count(const int* __restrict__ dst, float* __restrict__ deg, int E) {
    int i = blockIdx.x * blockDim.x + threadIdx.x;
    if (i < E) unsafeAtomicAdd(&deg[dst[i]], 1.0f);
}

__global__ void deg_invert(float* __restrict__ deg, int N) {
    int i = blockIdx.x * blockDim.x + threadIdx.x;
    if (i < N) deg[i] = 1.0f / fmaxf(deg[i], 1.0f);
}

// ---------------- scatter-add aggregation ----------------
// one thread per (edge, float4-chunk); DQ = D/4
template <int DQ>
__global__ void scatter_add(const float* __restrict__ h, const int* __restrict__ src,
                            const int* __restrict__ dst, float* __restrict__ agg, int E) {
    long tid = (long)blockIdx.x * blockDim.x + threadIdx.x;
    int e = (int)(tid / DQ);
    int c = (int)(tid % DQ);
    if (e >= E) return;
    int s = src[e], d = dst[e];
    float4 v = ((const float4*)h)[(long)s * DQ + c];
    float* o = agg + ((long)d * DQ + c) * 4;
    unsafeAtomicAdd(o + 0, v.x);
    unsafeAtomicAdd(o + 1, v.y);
    unsafeAtomicAdd(o + 2, v.z);
    unsafeAtomicAdd(o + 3, v.w);
}

// ---------------- fused GEMM ----------------
// C[N,M] = A1 @ B1 + (A2 * dinv[row]) @ B2 + bias    (A2 pass skipped if A2==nullptr)
// tiles: BM=64, BN=64, BK=16; 256 threads, 4x4 micro-tile per thread
__global__ __launch_bounds__(256) void gemm_fused(
    const float* __restrict__ A1, const float* __restrict__ A2,
    const float* __restrict__ dinv,
    const float* __restrict__ B1, const float* __restrict__ B2,
    const float* __restrict__ bias, float* __restrict__ C,
    int N, int K, int M)
{
    __shared__ float As[64][17];   // +1 pad: conflict-free column reads
    __shared__ float Bs[16][64];   // natural: 2-way aliasing = free

    const int tid = threadIdx.x;
    const int tx = tid & 15, ty = tid >> 4;
    const int row0 = blockIdx.x * 64;
    const int col0 = blockIdx.y * 64;

    const int lr = tid >> 2;   // A-load row 0..63
    const int lc = tid & 3;    // A-load float4 col 0..3
    const int br = tid >> 4;   // B-load row 0..15
    const int bc = tid & 15;   // B-load float4 col 0..15

    float acc[4][4] = {};

    for (int pass = 0; pass < 2; ++pass) {
        const float* A = pass ? A2 : A1;
        const float* B = pass ? B2 : B1;
        if (!A) break;
        float scale = 1.0f;
        if (pass) scale = (row0 + lr < N) ? dinv[row0 + lr] : 0.0f;

        for (int k0 = 0; k0 < K; k0 += 16) {
            float4 av = make_float4(0.f, 0.f, 0.f, 0.f);
            if (row0 + lr < N)
                av = *(const float4*)(A + (long)(row0 + lr) * K + k0 + lc * 4);
            if (pass) { av.x *= scale; av.y *= scale; av.z *= scale; av.w *= scale; }
            As[lr][lc * 4 + 0] = av.x;
            As[lr][lc * 4 + 1] = av.y;
            As[lr][lc * 4 + 2] = av.z;
            As[lr][lc * 4 + 3] = av.w;

            *(float4*)&Bs[br][bc * 4] =
                *(const float4*)(B + (long)(k0 + br) * M + col0 + bc * 4);

            __syncthreads();
            #pragma unroll
            for (int k = 0; k < 16; ++k) {
                float a[4];
                #pragma unroll
                for (int i = 0; i < 4; ++i) a[i] = As[ty * 4 + i][k];
                float4 bv = *(const float4*)&Bs[k][tx * 4];
                const float b[4] = {bv.x, bv.y, bv.z, bv.w};
                #pragma unroll
                for (int i = 0; i < 4; ++i)
                    #pragma unroll
                    for (int j = 0; j < 4; ++j)
                        acc[i][j] += a[i] * b[j];
            }
            __syncthreads();
        }
    }

    float4 bias4 = make_float4(0.f, 0.f, 0.f, 0.f);
    if (bias) bias4 = *(const float4*)(bias + col0 + tx * 4);

    #pragma unroll
    for (int i = 0; i < 4; ++i) {
        int r = row0 + ty * 4 + i;
        if (r < N) {
            float4 o;
            o.x = acc[i][0] + bias4.x;
            o.y = acc[i][1] + bias4.y;
            o.z = acc[i][2] + bias4.z;
            o.w = acc[i][3] + bias4.w;
            *(float4*)(C + (long)r * M + col0 + tx * 4) = o;
        }
    }
}

extern "C" void kernel_launch(void* const* d_in, const int* in_sizes, int n_in,
                              void* d_out, int out_size, void* d_ws, size_t ws_size,
                              hipStream_t stream) {
    const float* x    = (const float*)d_in[0];
    const int*   esrc = (const int*)d_in[1];
    const int*   edst = (const int*)d_in[2];
    const float* W0s  = (const float*)d_in[3];
    const float* W0n  = (const float*)d_in[4];
    const float* b0   = (const float*)d_in[5];
    const float* W1s  = (const float*)d_in[6];
    const float* W1n  = (const float*)d_in[7];
    const float* b1   = (const float*)d_in[8];
    const float* W2s  = (const float*)d_in[9];
    const float* W2n  = (const float*)d_in[10];
    const float* b2   = (const float*)d_in[11];
    const float* Wfc  = (const float*)d_in[12];
    const float* bfc  = (const float*)d_in[13];
    float* out = (float*)d_out;

    // workspace layout (floats)
    float* agg = (float*)d_ws;               // NN*HID
    float* hA  = agg + (size_t)NN * HID;     // NN*HID
    float* hB  = hA + (size_t)NN * HID;      // NN*HID
    float* deg = hB + (size_t)NN * HID;      // NN

    const int gRows = (NN + 63) / 64;

    // degree (+ invert in place -> deg holds 1/max(deg,1))
    hipMemsetAsync(deg, 0, (size_t)NN * sizeof(float), stream);
    deg_count<<<(NE + 255) / 256, 256, 0, stream>>>(edst, deg, NE);
    deg_invert<<<(NN + 255) / 256, 256, 0, stream>>>(deg, NN);

    // ---- layer 0: x(128) -> hA(256)
    hipMemsetAsync(agg, 0, (size_t)NN * F_IN * sizeof(float), stream);
    {
        long threads = (long)NE * (F_IN / 4);
        scatter_add<F_IN / 4><<<(threads + 255) / 256, 256, 0, stream>>>(x, esrc, edst, agg, NE);
    }
    gemm_fused<<<dim3(gRows, HID / 64), 256, 0, stream>>>(
        x, agg, deg, W0s, W0n, b0, hA, NN, F_IN, HID);

    // ---- layer 1: hA(256) -> hB(256)
    hipMemsetAsync(agg, 0, (size_t)NN * HID * sizeof(float), stream);
    {
        long threads = (long)NE * (HID / 4);
        scatter_add<HID / 4><<<(threads + 255) / 256, 256, 0, stream>>>(hA, esrc, edst, agg, NE);
    }
    gemm_fused<<<dim3(gRows, HID / 64), 256, 0, stream>>>(
        hA, agg, deg, W1s, W1n, b1, hB, NN, HID, HID);

    // ---- layer 2: hB(256) -> hA(256)
    hipMemsetAsync(agg, 0, (size_t)NN * HID * sizeof(float), stream);
    {
        long threads = (long)NE * (HID / 4);
        scatter_add<HID / 4><<<(threads + 255) / 256, 256, 0, stream>>>(hB, esrc, edst, agg, NE);
    }
    gemm_fused<<<dim3(gRows, HID / 64), 256, 0, stream>>>(
        hB, agg, deg, W2s, W2n, b2, hA, NN, HID, HID);

    // ---- fc: hA(256) -> out(64)
    gemm_fused<<<dim3(gRows, N_CLS / 64), 256, 0, stream>>>(
        hA, nullptr, nullptr, Wfc, nullptr, bfc, out, NN, HID, N_CLS);
}

// Round 2
// 995.246 us; speedup vs baseline: 7.4035x; 7.4035x over previous
//
#include <hip/hip_runtime.h>

#define NN 50000
#define NE 800000
#define F_IN 128
#define HID 256
#define N_CLS 64
#define SCAN_BLOCKS ((NN + 255) / 256)   // 196

// ---------------- CSR build ----------------
__global__ void hist_count(const int* __restrict__ dst, int* __restrict__ cnt, int E) {
    int i = blockIdx.x * blockDim.x + threadIdx.x;
    if (i < E) atomicAdd(&cnt[dst[i]], 1);
}

// per-block sums of cnt (256 elems per block)
__global__ void scan_block_sums(const int* __restrict__ cnt, int* __restrict__ blockSums, int n) {
    __shared__ int s[256];
    int t = threadIdx.x;
    int i = blockIdx.x * 256 + t;
    s[t] = (i < n) ? cnt[i] : 0;
    __syncthreads();
    for (int off = 128; off > 0; off >>= 1) {
        if (t < off) s[t] += s[t + off];
        __syncthreads();
    }
    if (t == 0) blockSums[blockIdx.x] = s[0];
}

// single-block exclusive scan of blockSums (nb <= 256)
__global__ void scan_top(int* __restrict__ blockSums, int nb) {
    __shared__ int s[256];
    int t = threadIdx.x;
    s[t] = (t < nb) ? blockSums[t] : 0;
    __syncthreads();
    for (int off = 1; off < 256; off <<= 1) {
        int v = (t >= off) ? s[t - off] : 0;
        __syncthreads();
        s[t] += v;
        __syncthreads();
    }
    if (t < nb) blockSums[t] = (t > 0) ? s[t - 1] : 0;  // exclusive
}

// per-block inclusive scan + base -> exclusive offsets
__global__ void scan_final(const int* __restrict__ cnt, const int* __restrict__ blockBase,
                           int* __restrict__ offs, int n) {
    __shared__ int s[256];
    int t = threadIdx.x;
    int i = blockIdx.x * 256 + t;
    int v = (i < n) ? cnt[i] : 0;
    s[t] = v;
    __syncthreads();
    for (int off = 1; off < 256; off <<= 1) {
        int u = (t >= off) ? s[t - off] : 0;
        __syncthreads();
        s[t] += u;
        __syncthreads();
    }
    if (i < n) offs[i] = blockBase[blockIdx.x] + s[t] - v;
    if (i == n - 1) offs[n] = blockBase[blockIdx.x] + s[t];
}

__global__ void make_dinv(const int* __restrict__ cnt, float* __restrict__ dinv, int n) {
    int i = blockIdx.x * blockDim.x + threadIdx.x;
    if (i < n) dinv[i] = 1.0f / (float)max(cnt[i], 1);
}

__global__ void csr_place(const int* __restrict__ src, const int* __restrict__ dst,
                          const int* __restrict__ offs, int* __restrict__ cursor,
                          int* __restrict__ csr_src, int E) {
    int e = blockIdx.x * blockDim.x + threadIdx.x;
    if (e < E) {
        int d = dst[e];
        int slot = atomicAdd(&cursor[d], 1);
        csr_src[offs[d] + slot] = src[e];
    }
}

// ---------------- pull (gather) aggregation ----------------
// DQ = D/4 lanes per node; group of DQ threads handles one node.
// agg[node] = dinv[node] * sum_{e in csr[node]} h[csr_src[e]]
template <int DQ>
__global__ __launch_bounds__(256) void gather_agg(
    const float* __restrict__ h, const int* __restrict__ csr_src,
    const int* __restrict__ offs, const float* __restrict__ dinv,
    float* __restrict__ agg, int N)
{
    const int npb = 256 / DQ;
    int node = blockIdx.x * npb + threadIdx.x / DQ;
    int lane = threadIdx.x % DQ;
    if (node >= N) return;
    int beg = offs[node], end = offs[node + 1];
    float4 acc = make_float4(0.f, 0.f, 0.f, 0.f);
    int e = beg;
    // 2x unrolled to expose independent loads
    for (; e + 1 < end; e += 2) {
        int s0 = csr_src[e], s1 = csr_src[e + 1];
        float4 v0 = ((const float4*)h)[(long)s0 * DQ + lane];
        float4 v1 = ((const float4*)h)[(long)s1 * DQ + lane];
        acc.x += v0.x + v1.x; acc.y += v0.y + v1.y;
        acc.z += v0.z + v1.z; acc.w += v0.w + v1.w;
    }
    if (e < end) {
        int s0 = csr_src[e];
        float4 v0 = ((const float4*)h)[(long)s0 * DQ + lane];
        acc.x += v0.x; acc.y += v0.y; acc.z += v0.z; acc.w += v0.w;
    }
    float sc = dinv[node];
    acc.x *= sc; acc.y *= sc; acc.z *= sc; acc.w *= sc;
    ((float4*)agg)[(long)node * DQ + lane] = acc;
}

// ---------------- fused GEMM ----------------
// C[N,M] = A1 @ B1 + A2 @ B2 + bias    (A2 pass skipped if A2==nullptr)
// tiles: BM=64, BN=64, BK=16; 256 threads, 4x4 micro-tile per thread
__global__ __launch_bounds__(256) void gemm_fused(
    const float* __restrict__ A1, const float* __restrict__ A2,
    const float* __restrict__ B1, const float* __restrict__ B2,
    const float* __restrict__ bias, float* __restrict__ C,
    int N, int K, int M)
{
    __shared__ float As[64][17];   // +1 pad: conflict-free column reads
    __shared__ float Bs[16][64];   // natural: 2-way aliasing = free

    const int tid = threadIdx.x;
    const int tx = tid & 15, ty = tid >> 4;
    const int row0 = blockIdx.x * 64;
    const int col0 = blockIdx.y * 64;

    const int lr = tid >> 2;   // A-load row 0..63
    const int lc = tid & 3;    // A-load float4 col 0..3
    const int br = tid >> 4;   // B-load row 0..15
    const int bc = tid & 15;   // B-load float4 col 0..15

    float acc[4][4] = {};

    for (int pass = 0; pass < 2; ++pass) {
        const float* A = pass ? A2 : A1;
        const float* B = pass ? B2 : B1;
        if (!A) break;

        for (int k0 = 0; k0 < K; k0 += 16) {
            float4 av = make_float4(0.f, 0.f, 0.f, 0.f);
            if (row0 + lr < N)
                av = *(const float4*)(A + (long)(row0 + lr) * K + k0 + lc * 4);
            As[lr][lc * 4 + 0] = av.x;
            As[lr][lc * 4 + 1] = av.y;
            As[lr][lc * 4 + 2] = av.z;
            As[lr][lc * 4 + 3] = av.w;

            *(float4*)&Bs[br][bc * 4] =
                *(const float4*)(B + (long)(k0 + br) * M + col0 + bc * 4);

            __syncthreads();
            #pragma unroll
            for (int k = 0; k < 16; ++k) {
                float a[4];
                #pragma unroll
                for (int i = 0; i < 4; ++i) a[i] = As[ty * 4 + i][k];
                float4 bv = *(const float4*)&Bs[k][tx * 4];
                const float b[4] = {bv.x, bv.y, bv.z, bv.w};
                #pragma unroll
                for (int i = 0; i < 4; ++i)
                    #pragma unroll
                    for (int j = 0; j < 4; ++j)
                        acc[i][j] += a[i] * b[j];
            }
            __syncthreads();
        }
    }

    float4 bias4 = make_float4(0.f, 0.f, 0.f, 0.f);
    if (bias) bias4 = *(const float4*)(bias + col0 + tx * 4);

    #pragma unroll
    for (int i = 0; i < 4; ++i) {
        int r = row0 + ty * 4 + i;
        if (r < N) {
            float4 o;
            o.x = acc[i][0] + bias4.x;
            o.y = acc[i][1] + bias4.y;
            o.z = acc[i][2] + bias4.z;
            o.w = acc[i][3] + bias4.w;
            *(float4*)(C + (long)r * M + col0 + tx * 4) = o;
        }
    }
}

extern "C" void kernel_launch(void* const* d_in, const int* in_sizes, int n_in,
                              void* d_out, int out_size, void* d_ws, size_t ws_size,
                              hipStream_t stream) {
    const float* x    = (const float*)d_in[0];
    const int*   esrc = (const int*)d_in[1];
    const int*   edst = (const int*)d_in[2];
    const float* W0s  = (const float*)d_in[3];
    const float* W0n  = (const float*)d_in[4];
    const float* b0   = (const float*)d_in[5];
    const float* W1s  = (const float*)d_in[6];
    const float* W1n  = (const float*)d_in[7];
    const float* b1   = (const float*)d_in[8];
    const float* W2s  = (const float*)d_in[9];
    const float* W2n  = (const float*)d_in[10];
    const float* b2   = (const float*)d_in[11];
    const float* Wfc  = (const float*)d_in[12];
    const float* bfc  = (const float*)d_in[13];
    float* out = (float*)d_out;

    // workspace layout
    float* agg  = (float*)d_ws;                    // NN*HID floats
    float* hA   = agg + (size_t)NN * HID;          // NN*HID
    float* hB   = hA + (size_t)NN * HID;           // NN*HID
    float* dinv = hB + (size_t)NN * HID;           // NN (multiple of 4 -> keeps alignment)
    int* cnt      = (int*)(dinv + NN);             // NN
    int* offs     = cnt + NN;                      // NN+1
    int* cursor   = offs + NN + 1;                 // NN
    int* csr_src  = cursor + NN;                   // NE
    int* blockSums = csr_src + NE;                 // SCAN_BLOCKS

    const int gRows = (NN + 63) / 64;

    // ---- CSR build (per call; same work every call) ----
    hipMemsetAsync(cnt, 0, (size_t)NN * sizeof(int), stream);
    hipMemsetAsync(cursor, 0, (size_t)NN * sizeof(int), stream);
    hist_count<<<(NE + 255) / 256, 256, 0, stream>>>(edst, cnt, NE);
    scan_block_sums<<<SCAN_BLOCKS, 256, 0, stream>>>(cnt, blockSums, NN);
    scan_top<<<1, 256, 0, stream>>>(blockSums, SCAN_BLOCKS);
    scan_final<<<SCAN_BLOCKS, 256, 0, stream>>>(cnt, blockSums, offs, NN);
    make_dinv<<<(NN + 255) / 256, 256, 0, stream>>>(cnt, dinv, NN);
    csr_place<<<(NE + 255) / 256, 256, 0, stream>>>(esrc, edst, offs, cursor, csr_src, NE);

    // ---- layer 0: x(128) -> hA(256)
    gather_agg<F_IN / 4><<<(NN * (F_IN / 4) + 255) / 256, 256, 0, stream>>>(
        x, csr_src, offs, dinv, agg, NN);
    gemm_fused<<<dim3(gRows, HID / 64), 256, 0, stream>>>(
        x, agg, W0s, W0n, b0, hA, NN, F_IN, HID);

    // ---- layer 1: hA(256) -> hB(256)
    gather_agg<HID / 4><<<(NN * (HID / 4) + 255) / 256, 256, 0, stream>>>(
        hA, csr_src, offs, dinv, agg, NN);
    gemm_fused<<<dim3(gRows, HID / 64), 256, 0, stream>>>(
        hA, agg, W1s, W1n, b1, hB, NN, HID, HID);

    // ---- layer 2: hB(256) -> hA(256)
    gather_agg<HID / 4><<<(NN * (HID / 4) + 255) / 256, 256, 0, stream>>>(
        hB, csr_src, offs, dinv, agg, NN);
    gemm_fused<<<dim3(gRows, HID / 64), 256, 0, stream>>>(
        hB, agg, W2s, W2n, b2, hA, NN, HID, HID);

    // ---- fc: hA(256) -> out(64)
    gemm_fused<<<dim3(gRows, N_CLS / 64), 256, 0, stream>>>(
        hA, nullptr, Wfc, nullptr, bfc, out, NN, HID, N_CLS);
}

// Round 3
// 466.746 us; speedup vs baseline: 15.7866x; 2.1323x over previous
//
#include <hip/hip_runtime.h>

#define NN 50000
#define NE 800000
#define F_IN 128
#define HID 256
#define N_CLS 64
#define SCAN_BLOCKS ((NN + 255) / 256)   // 196

typedef _Float16 half8 __attribute__((ext_vector_type(8)));
typedef float f32x4 __attribute__((ext_vector_type(4)));

// ================= CSR build =================
__global__ void hist_count(const int* __restrict__ dst, int* __restrict__ cnt, int E) {
    int i = blockIdx.x * blockDim.x + threadIdx.x;
    if (i < E) atomicAdd(&cnt[dst[i]], 1);
}

__global__ void scan_block_sums(const int* __restrict__ cnt, int* __restrict__ blockSums, int n) {
    __shared__ int s[256];
    int t = threadIdx.x;
    int i = blockIdx.x * 256 + t;
    s[t] = (i < n) ? cnt[i] : 0;
    __syncthreads();
    for (int off = 128; off > 0; off >>= 1) {
        if (t < off) s[t] += s[t + off];
        __syncthreads();
    }
    if (t == 0) blockSums[blockIdx.x] = s[0];
}

__global__ void scan_top(int* __restrict__ blockSums, int nb) {
    __shared__ int s[256];
    int t = threadIdx.x;
    s[t] = (t < nb) ? blockSums[t] : 0;
    __syncthreads();
    for (int off = 1; off < 256; off <<= 1) {
        int v = (t >= off) ? s[t - off] : 0;
        __syncthreads();
        s[t] += v;
        __syncthreads();
    }
    if (t < nb) blockSums[t] = (t > 0) ? s[t - 1] : 0;  // exclusive
}

__global__ void scan_final(const int* __restrict__ cnt, const int* __restrict__ blockBase,
                           int* __restrict__ offs, int n) {
    __shared__ int s[256];
    int t = threadIdx.x;
    int i = blockIdx.x * 256 + t;
    int v = (i < n) ? cnt[i] : 0;
    s[t] = v;
    __syncthreads();
    for (int off = 1; off < 256; off <<= 1) {
        int u = (t >= off) ? s[t - off] : 0;
        __syncthreads();
        s[t] += u;
        __syncthreads();
    }
    if (i < n) offs[i] = blockBase[blockIdx.x] + s[t] - v;
    if (i == n - 1) offs[n] = blockBase[blockIdx.x] + s[t];
}

__global__ void make_dinv(const int* __restrict__ cnt, float* __restrict__ dinv, int n) {
    int i = blockIdx.x * blockDim.x + threadIdx.x;
    if (i < n) dinv[i] = 1.0f / (float)max(cnt[i], 1);
}

__global__ void csr_place(const int* __restrict__ src, const int* __restrict__ dst,
                          const int* __restrict__ offs, int* __restrict__ cursor,
                          int* __restrict__ csr_src, int E) {
    int e = blockIdx.x * blockDim.x + threadIdx.x;
    if (e < E) {
        int d = dst[e];
        int slot = atomicAdd(&cursor[d], 1);
        csr_src[offs[d] + slot] = src[e];
    }
}

// ================= fp16 conversions =================
// x fp32 [N][128] -> hcat0 cols 0..127 (row stride 256 halves)
__global__ void convert_x(const float* __restrict__ x, _Float16* __restrict__ hc, int N) {
    int i = blockIdx.x * blockDim.x + threadIdx.x;  // over N*32 float4s
    if (i >= N * (F_IN / 4)) return;
    int n = i / (F_IN / 4), c = i % (F_IN / 4);
    float4 v = ((const float4*)x)[(size_t)n * (F_IN / 4) + c];
    _Float16* o = hc + (size_t)n * 256 + c * 4;
    o[0] = (_Float16)v.x; o[1] = (_Float16)v.y; o[2] = (_Float16)v.z; o[3] = (_Float16)v.w;
}

// W pair (Ws,Wn), each [Kh][M] fp32 -> WT fp16 [M][2*Kh] (row-major in k)
__global__ void wt_pair(const float* __restrict__ Ws, const float* __restrict__ Wn,
                        _Float16* __restrict__ WT, int Kh, int M) {
    int idx = blockIdx.x * blockDim.x + threadIdx.x;
    int Kt = 2 * Kh;
    if (idx >= M * Kt) return;
    int m = idx / Kt, k = idx % Kt;
    float v = (k < Kh) ? Ws[(size_t)k * M + m] : Wn[(size_t)(k - Kh) * M + m];
    WT[(size_t)m * Kt + k] = (_Float16)v;
}

// single W [K][M] fp32 -> WT fp16 [M][K]
__global__ void wt_single(const float* __restrict__ W, _Float16* __restrict__ WT, int K, int M) {
    int idx = blockIdx.x * blockDim.x + threadIdx.x;
    if (idx >= M * K) return;
    int m = idx / K, k = idx % K;
    WT[(size_t)m * K + k] = (_Float16)W[(size_t)k * M + m];
}

// ================= gather (pull) aggregation, fp16 in/out =================
// L = D/8 lanes per node; lane loads 8 halves, accumulates fp32, writes 8 halves.
template <int L>
__global__ __launch_bounds__(256) void gather_h(
    const _Float16* __restrict__ in, int sin,
    const int* __restrict__ csr_src, const int* __restrict__ offs,
    const float* __restrict__ dinv,
    _Float16* __restrict__ outp, int sout, int N)
{
    const int npb = 256 / L;
    int node = blockIdx.x * npb + threadIdx.x / L;
    int lane = threadIdx.x % L;
    if (node >= N) return;
    int beg = offs[node], end = offs[node + 1];
    float acc[8] = {};
    int e = beg;
    for (; e + 1 < end; e += 2) {
        int s0 = csr_src[e], s1 = csr_src[e + 1];
        half8 v0 = *(const half8*)(in + (size_t)s0 * sin + lane * 8);
        half8 v1 = *(const half8*)(in + (size_t)s1 * sin + lane * 8);
        #pragma unroll
        for (int j = 0; j < 8; ++j) acc[j] += (float)v0[j] + (float)v1[j];
    }
    if (e < end) {
        half8 v0 = *(const half8*)(in + (size_t)csr_src[e] * sin + lane * 8);
        #pragma unroll
        for (int j = 0; j < 8; ++j) acc[j] += (float)v0[j];
    }
    float sc = dinv[node];
    half8 o;
    #pragma unroll
    for (int j = 0; j < 8; ++j) o[j] = (_Float16)(acc[j] * sc);
    *(half8*)(outp + (size_t)node * sout + lane * 8) = o;
}

// ================= MFMA GEMM =================
// C[N,M-block] = A[N,K] @ BT[M,K]^T + bias ; A,BT fp16; acc fp32.
// BM x BN tile, 256 threads (4 waves), 16x16x32 f16 MFMA.
template <int BM, int BN, bool OUT_F32>
__global__ __launch_bounds__(256) void gemm_mfma(
    const _Float16* __restrict__ A, int lda,
    const _Float16* __restrict__ BT,           // [M][K] fp16
    const float* __restrict__ bias,
    void* __restrict__ Cout, int ldc,
    int N, int K)
{
    constexpr int LP = 40;                      // LDS pitch in halves (32 + 8 pad)
    constexpr int WC = BN / 64;                 // waves along N
    constexpr int WR = 4 / WC;                  // waves along M
    constexpr int WTM = BM / WR;                // wave tile M
    constexpr int MT = WTM / 16;                // MFMA tiles per wave, M
    constexpr int NT = 4;                       // 64/16

    __shared__ _Float16 As[BM * LP];
    __shared__ _Float16 Bs[BN * LP];

    const int tid = threadIdx.x;
    const int wave = tid >> 6;
    const int lane = tid & 63;
    const int l15 = lane & 15;
    const int quad = lane >> 4;
    const int wrow = wave / WC;
    const int wcol = wave % WC;
    const int m_base = wrow * WTM;
    const int n_base = wcol * 64;

    const int row0 = blockIdx.x * BM;
    const int col0 = blockIdx.y * BN;

    f32x4 acc[MT][NT] = {};

    for (int k0 = 0; k0 < K; k0 += 32) {
        // stage A: BM rows x 32 halves
        #pragma unroll
        for (int r = 0; r < BM / 64; ++r) {
            int idx = r * 256 + tid;
            int row = idx >> 2, chunk = idx & 3;
            int grow = row0 + row; if (grow > N - 1) grow = N - 1;
            half8 v = *(const half8*)(A + (size_t)grow * lda + k0 + chunk * 8);
            *(half8*)&As[row * LP + chunk * 8] = v;
        }
        // stage B: BN rows (n) x 32 halves from BT
        #pragma unroll
        for (int r = 0; r < BN / 64; ++r) {
            int idx = r * 256 + tid;
            int row = idx >> 2, chunk = idx & 3;
            half8 v = *(const half8*)(BT + (size_t)(col0 + row) * K + k0 + chunk * 8);
            *(half8*)&Bs[row * LP + chunk * 8] = v;
        }
        __syncthreads();

        half8 af[MT], bf[NT];
        #pragma unroll
        for (int i = 0; i < MT; ++i)
            af[i] = *(const half8*)&As[(m_base + i * 16 + l15) * LP + quad * 8];
        #pragma unroll
        for (int j = 0; j < NT; ++j)
            bf[j] = *(const half8*)&Bs[(n_base + j * 16 + l15) * LP + quad * 8];
        #pragma unroll
        for (int i = 0; i < MT; ++i)
            #pragma unroll
            for (int j = 0; j < NT; ++j)
                acc[i][j] = __builtin_amdgcn_mfma_f32_16x16x32_f16(af[i], bf[j], acc[i][j], 0, 0, 0);
        __syncthreads();
    }

    // epilogue: C/D layout col=lane&15, row=quad*4+reg
    #pragma unroll
    for (int i = 0; i < MT; ++i) {
        #pragma unroll
        for (int j = 0; j < NT; ++j) {
            int col_g = col0 + n_base + j * 16 + l15;
            float bv = bias[col_g];
            #pragma unroll
            for (int r = 0; r < 4; ++r) {
                int row_g = row0 + m_base + i * 16 + quad * 4 + r;
                if (row_g < N) {
                    float v = acc[i][j][r] + bv;
                    if (OUT_F32)
                        ((float*)Cout)[(size_t)row_g * ldc + col_g] = v;
                    else
                        ((_Float16*)Cout)[(size_t)row_g * ldc + col_g] = (_Float16)v;
                }
            }
        }
    }
}

extern "C" void kernel_launch(void* const* d_in, const int* in_sizes, int n_in,
                              void* d_out, int out_size, void* d_ws, size_t ws_size,
                              hipStream_t stream) {
    const float* x    = (const float*)d_in[0];
    const int*   esrc = (const int*)d_in[1];
    const int*   edst = (const int*)d_in[2];
    const float* W0s  = (const float*)d_in[3];
    const float* W0n  = (const float*)d_in[4];
    const float* b0   = (const float*)d_in[5];
    const float* W1s  = (const float*)d_in[6];
    const float* W1n  = (const float*)d_in[7];
    const float* b1   = (const float*)d_in[8];
    const float* W2s  = (const float*)d_in[9];
    const float* W2n  = (const float*)d_in[10];
    const float* b2   = (const float*)d_in[11];
    const float* Wfc  = (const float*)d_in[12];
    const float* bfc  = (const float*)d_in[13];
    float* out = (float*)d_out;

    // ---- workspace layout (bytes via half units) ----
    _Float16* hcat0 = (_Float16*)d_ws;                    // N x 256  [x | agg0]
    _Float16* hcat1 = hcat0 + (size_t)NN * 256;           // N x 512  [h1 | agg1]
    _Float16* hcat2 = hcat1 + (size_t)NN * 512;           // N x 512  [h2 | agg2]
    _Float16* h3    = hcat2 + (size_t)NN * 512;           // N x 256
    _Float16* Wc0T  = h3    + (size_t)NN * 256;           // 256 x 256
    _Float16* Wc1T  = Wc0T + 256 * 256;                   // 256 x 512
    _Float16* Wc2T  = Wc1T + 256 * 512;                   // 256 x 512
    _Float16* WfcT  = Wc2T + 256 * 512;                   // 64 x 256
    float* dinv     = (float*)(WfcT + 64 * 256);          // N
    int* cnt        = (int*)(dinv + NN);                  // N
    int* offs       = cnt + NN;                           // N+1
    int* cursor     = offs + NN + 1;                      // N
    int* csr_src    = cursor + NN;                        // E
    int* blockSums  = csr_src + NE;                       // SCAN_BLOCKS

    const int gRows = (NN + 127) / 128;                   // 391

    // ---- CSR build ----
    hipMemsetAsync(cnt, 0, (size_t)NN * sizeof(int), stream);
    hipMemsetAsync(cursor, 0, (size_t)NN * sizeof(int), stream);
    hist_count<<<(NE + 255) / 256, 256, 0, stream>>>(edst, cnt, NE);
    scan_block_sums<<<SCAN_BLOCKS, 256, 0, stream>>>(cnt, blockSums, NN);
    scan_top<<<1, 256, 0, stream>>>(blockSums, SCAN_BLOCKS);
    scan_final<<<SCAN_BLOCKS, 256, 0, stream>>>(cnt, blockSums, offs, NN);
    make_dinv<<<(NN + 255) / 256, 256, 0, stream>>>(cnt, dinv, NN);
    csr_place<<<(NE + 255) / 256, 256, 0, stream>>>(esrc, edst, offs, cursor, csr_src, NE);

    // ---- fp16 prep ----
    convert_x<<<(NN * (F_IN / 4) + 255) / 256, 256, 0, stream>>>(x, hcat0, NN);
    wt_pair<<<(HID * 256 + 255) / 256, 256, 0, stream>>>(W0s, W0n, Wc0T, F_IN, HID);
    wt_pair<<<(HID * 512 + 255) / 256, 256, 0, stream>>>(W1s, W1n, Wc1T, HID, HID);
    wt_pair<<<(HID * 512 + 255) / 256, 256, 0, stream>>>(W2s, W2n, Wc2T, HID, HID);
    wt_single<<<(N_CLS * HID + 255) / 256, 256, 0, stream>>>(Wfc, WfcT, HID, N_CLS);

    // ---- layer 0: hcat0 = [x16 | agg0] (K=256) -> h1 (hcat1 cols 0..255)
    gather_h<F_IN / 8><<<(NN * (F_IN / 8) + 255) / 256, 256, 0, stream>>>(
        hcat0, 256, csr_src, offs, dinv, hcat0 + 128, 256, NN);
    gemm_mfma<128, 128, false><<<dim3(gRows, 2), 256, 0, stream>>>(
        hcat0, 256, Wc0T, b0, hcat1, 512, NN, 256);

    // ---- layer 1: hcat1 = [h1 | agg1] (K=512) -> h2 (hcat2 cols 0..255)
    gather_h<HID / 8><<<(NN * (HID / 8) + 255) / 256, 256, 0, stream>>>(
        hcat1, 512, csr_src, offs, dinv, hcat1 + 256, 512, NN);
    gemm_mfma<128, 128, false><<<dim3(gRows, 2), 256, 0, stream>>>(
        hcat1, 512, Wc1T, b1, hcat2, 512, NN, 512);

    // ---- layer 2: hcat2 = [h2 | agg2] (K=512) -> h3
    gather_h<HID / 8><<<(NN * (HID / 8) + 255) / 256, 256, 0, stream>>>(
        hcat2, 512, csr_src, offs, dinv, hcat2 + 256, 512, NN);
    gemm_mfma<128, 128, false><<<dim3(gRows, 2), 256, 0, stream>>>(
        hcat2, 512, Wc2T, b2, h3, 256, NN, 512);

    // ---- fc: h3 (K=256) -> out fp32 (M=64)
    gemm_mfma<128, 64, true><<<dim3(gRows, 1), 256, 0, stream>>>(
        h3, 256, WfcT, bfc, out, 64, NN, 256);
}

// Round 4
// 411.214 us; speedup vs baseline: 17.9185x; 1.1350x over previous
//
#include <hip/hip_runtime.h>

#define NN 50000
#define NE 800000
#define F_IN 128
#define HID 256
#define N_CLS 64
#define SCAN_BLOCKS ((NN + 255) / 256)   // 196
#define CROWS 515                        // basis: X,AX,A2X,A3X (4*128) + 1,d,Ad

typedef _Float16 half8 __attribute__((ext_vector_type(8)));
typedef float f32x4 __attribute__((ext_vector_type(4)));

// ================= CSR build =================
__global__ void hist_count(const int* __restrict__ dst, int* __restrict__ cnt, int E) {
    int i = blockIdx.x * blockDim.x + threadIdx.x;
    if (i < E) atomicAdd(&cnt[dst[i]], 1);
}

__global__ void scan_block_sums(const int* __restrict__ cnt, int* __restrict__ blockSums, int n) {
    __shared__ int s[256];
    int t = threadIdx.x;
    int i = blockIdx.x * 256 + t;
    s[t] = (i < n) ? cnt[i] : 0;
    __syncthreads();
    for (int off = 128; off > 0; off >>= 1) {
        if (t < off) s[t] += s[t + off];
        __syncthreads();
    }
    if (t == 0) blockSums[blockIdx.x] = s[0];
}

__global__ void scan_top(int* __restrict__ blockSums, int nb) {
    __shared__ int s[256];
    int t = threadIdx.x;
    s[t] = (t < nb) ? blockSums[t] : 0;
    __syncthreads();
    for (int off = 1; off < 256; off <<= 1) {
        int v = (t >= off) ? s[t - off] : 0;
        __syncthreads();
        s[t] += v;
        __syncthreads();
    }
    if (t < nb) blockSums[t] = (t > 0) ? s[t - 1] : 0;  // exclusive
}

__global__ void scan_final(const int* __restrict__ cnt, const int* __restrict__ blockBase,
                           int* __restrict__ offs, int n) {
    __shared__ int s[256];
    int t = threadIdx.x;
    int i = blockIdx.x * 256 + t;
    int v = (i < n) ? cnt[i] : 0;
    s[t] = v;
    __syncthreads();
    for (int off = 1; off < 256; off <<= 1) {
        int u = (t >= off) ? s[t - off] : 0;
        __syncthreads();
        s[t] += u;
        __syncthreads();
    }
    if (i < n) offs[i] = blockBase[blockIdx.x] + s[t] - v;
    if (i == n - 1) offs[n] = blockBase[blockIdx.x] + s[t];
}

__global__ void make_dinv(const int* __restrict__ cnt, float* __restrict__ dinv,
                          float* __restrict__ dvec, int n) {
    int i = blockIdx.x * blockDim.x + threadIdx.x;
    if (i < n) {
        int c = cnt[i];
        dinv[i] = 1.0f / (float)max(c, 1);
        dvec[i] = (c > 0) ? 1.0f : 0.0f;
    }
}

__global__ void csr_place(const int* __restrict__ src, const int* __restrict__ dst,
                          const int* __restrict__ offs, int* __restrict__ cursor,
                          int* __restrict__ csr_src, int E) {
    int e = blockIdx.x * blockDim.x + threadIdx.x;
    if (e < E) {
        int d = dst[e];
        int slot = atomicAdd(&cursor[d], 1);
        csr_src[offs[d] + slot] = src[e];
    }
}

// ================= fp16 conversions =================
// x fp32 [N][128] -> G cols 0..127 (row stride 512 halves)
__global__ void convert_x(const float* __restrict__ x, _Float16* __restrict__ G, int N) {
    int i = blockIdx.x * blockDim.x + threadIdx.x;
    if (i >= N * (F_IN / 4)) return;
    int n = i / (F_IN / 4), c = i % (F_IN / 4);
    float4 v = ((const float4*)x)[(size_t)n * (F_IN / 4) + c];
    _Float16* o = G + (size_t)n * 512 + c * 4;
    o[0] = (_Float16)v.x; o[1] = (_Float16)v.y; o[2] = (_Float16)v.z; o[3] = (_Float16)v.w;
}

// ================= affine-map composition (515-row coefficient matrices) =================
// C1 rows: [0,128)=W0s, [128,256)=W0n, 512=b0, else 0.
__global__ void init_C1(const float* __restrict__ W0s, const float* __restrict__ W0n,
                        const float* __restrict__ b0, float* __restrict__ C) {
    int idx = blockIdx.x * blockDim.x + threadIdx.x;
    if (idx >= CROWS * 256) return;
    int r = idx / 256, m = idx % 256;
    float v = 0.0f;
    if (r < 128) v = W0s[r * 256 + m];
    else if (r < 256) v = W0n[(r - 128) * 256 + m];
    else if (r == 512) v = b0[m];
    C[idx] = v;
}

// shiftA: basis X->AX->A2X->A3X (row blocks +128), 1->d (512->513), d->Ad (513->514)
__global__ void shift_copy(const float* __restrict__ in, float* __restrict__ outp) {
    int idx = blockIdx.x * blockDim.x + threadIdx.x;
    if (idx >= CROWS * 256) return;
    int r = idx / 256, k = idx % 256;
    float v = 0.0f;
    if (r >= 128 && r < 512) v = in[(r - 128) * 256 + k];
    else if (r == 513) v = in[512 * 256 + k];
    else if (r == 514) v = in[513 * 256 + k];
    outp[idx] = v;
}

__global__ void add_row(float* __restrict__ rowp, const float* __restrict__ b, int M) {
    int m = threadIdx.x;
    if (m < M) rowp[m] += b[m];
}

// V fp32 [515][64]; rows<512 -> VT fp16 [64][512]
__global__ void vt_convert(const float* __restrict__ V, _Float16* __restrict__ VT) {
    int idx = blockIdx.x * blockDim.x + threadIdx.x;
    if (idx >= 64 * 512) return;
    int m = idx / 512, k = idx % 512;
    VT[idx] = (_Float16)V[k * 64 + m];
}

// ================= fp32 tiled GEMM (for small compose GEMMs) =================
// C[N,M] = A1 @ B1 + A2 @ B2 + bias ; A2/bias nullable. BM=BN=64, BK=16.
__global__ __launch_bounds__(256) void gemm_fused32(
    const float* __restrict__ A1, const float* __restrict__ A2,
    const float* __restrict__ B1, const float* __restrict__ B2,
    const float* __restrict__ bias, float* __restrict__ C,
    int N, int K, int M)
{
    __shared__ float As[64][17];
    __shared__ float Bs[16][64];

    const int tid = threadIdx.x;
    const int tx = tid & 15, ty = tid >> 4;
    const int row0 = blockIdx.x * 64;
    const int col0 = blockIdx.y * 64;

    const int lr = tid >> 2;
    const int lc = tid & 3;
    const int br = tid >> 4;
    const int bc = tid & 15;

    float acc[4][4] = {};

    for (int pass = 0; pass < 2; ++pass) {
        const float* A = pass ? A2 : A1;
        const float* B = pass ? B2 : B1;
        if (!A) break;

        for (int k0 = 0; k0 < K; k0 += 16) {
            float4 av = make_float4(0.f, 0.f, 0.f, 0.f);
            if (row0 + lr < N)
                av = *(const float4*)(A + (size_t)(row0 + lr) * K + k0 + lc * 4);
            As[lr][lc * 4 + 0] = av.x;
            As[lr][lc * 4 + 1] = av.y;
            As[lr][lc * 4 + 2] = av.z;
            As[lr][lc * 4 + 3] = av.w;

            *(float4*)&Bs[br][bc * 4] =
                *(const float4*)(B + (size_t)(k0 + br) * M + col0 + bc * 4);

            __syncthreads();
            #pragma unroll
            for (int k = 0; k < 16; ++k) {
                float a[4];
                #pragma unroll
                for (int i = 0; i < 4; ++i) a[i] = As[ty * 4 + i][k];
                float4 bv = *(const float4*)&Bs[k][tx * 4];
                const float b[4] = {bv.x, bv.y, bv.z, bv.w};
                #pragma unroll
                for (int i = 0; i < 4; ++i)
                    #pragma unroll
                    for (int j = 0; j < 4; ++j)
                        acc[i][j] += a[i] * b[j];
            }
            __syncthreads();
        }
    }

    float4 bias4 = make_float4(0.f, 0.f, 0.f, 0.f);
    if (bias) bias4 = *(const float4*)(bias + col0 + tx * 4);

    #pragma unroll
    for (int i = 0; i < 4; ++i) {
        int r = row0 + ty * 4 + i;
        if (r < N) {
            float4 o;
            o.x = acc[i][0] + bias4.x;
            o.y = acc[i][1] + bias4.y;
            o.z = acc[i][2] + bias4.z;
            o.w = acc[i][3] + bias4.w;
            *(float4*)(C + (size_t)r * M + col0 + tx * 4) = o;
        }
    }
}

// ================= gather: one A-application on a 128-wide fp16 block =================
// 16 lanes per node; lane loads half8 (16B); fp32 accumulate; 4x unroll for ILP.
__global__ __launch_bounds__(256) void gather128(
    const _Float16* __restrict__ G, int in_off, int out_off,
    const int* __restrict__ csr_src, const int* __restrict__ offs,
    const float* __restrict__ dinv, _Float16* __restrict__ Gout, int N)
{
    int node = blockIdx.x * 16 + (threadIdx.x >> 4);
    int lane = threadIdx.x & 15;
    if (node >= N) return;
    int beg = offs[node], end = offs[node + 1];
    float acc[8] = {};
    int e = beg;
    for (; e + 3 < end; e += 4) {
        int s0 = csr_src[e], s1 = csr_src[e + 1];
        int s2 = csr_src[e + 2], s3 = csr_src[e + 3];
        half8 v0 = *(const half8*)(G + (size_t)s0 * 512 + in_off + lane * 8);
        half8 v1 = *(const half8*)(G + (size_t)s1 * 512 + in_off + lane * 8);
        half8 v2 = *(const half8*)(G + (size_t)s2 * 512 + in_off + lane * 8);
        half8 v3 = *(const half8*)(G + (size_t)s3 * 512 + in_off + lane * 8);
        #pragma unroll
        for (int j = 0; j < 8; ++j)
            acc[j] += ((float)v0[j] + (float)v1[j]) + ((float)v2[j] + (float)v3[j]);
    }
    for (; e < end; ++e) {
        half8 v = *(const half8*)(G + (size_t)csr_src[e] * 512 + in_off + lane * 8);
        #pragma unroll
        for (int j = 0; j < 8; ++j) acc[j] += (float)v[j];
    }
    float sc = dinv[node];
    half8 o;
    #pragma unroll
    for (int j = 0; j < 8; ++j) o[j] = (_Float16)(acc[j] * sc);
    *(half8*)(Gout + (size_t)node * 512 + out_off + lane * 8) = o;
}

// Ad[i] = dinv[i] * sum_{e in csr[i]} dvec[src]
__global__ void compute_Ad(const float* __restrict__ dvec, const float* __restrict__ dinv,
                           const int* __restrict__ csr_src, const int* __restrict__ offs,
                           float* __restrict__ Ad, int N) {
    int i = blockIdx.x * blockDim.x + threadIdx.x;
    if (i >= N) return;
    float s = 0.0f;
    int end = offs[i + 1];
    for (int e = offs[i]; e < end; ++e) s += dvec[csr_src[e]];
    Ad[i] = s * dinv[i];
}

// ================= final MFMA GEMM: out[N][64] = G[N][512] @ VT^T + c1 + d*c2 + Ad*c3
__global__ __launch_bounds__(256) void gemm_final(
    const _Float16* __restrict__ G, const _Float16* __restrict__ VT,
    const float* __restrict__ Vext,   // [3][64]: c1, c2, c3
    const float* __restrict__ dvec, const float* __restrict__ Advec,
    float* __restrict__ out, int N)
{
    constexpr int LP = 40;
    __shared__ _Float16 As[128 * LP];
    __shared__ _Float16 Bs[64 * LP];

    const int tid = threadIdx.x;
    const int wave = tid >> 6;
    const int lane = tid & 63;
    const int l15 = lane & 15;
    const int quad = lane >> 4;
    const int m_base = wave * 32;
    const int row0 = blockIdx.x * 128;

    f32x4 acc[2][4] = {};

    for (int k0 = 0; k0 < 512; k0 += 32) {
        #pragma unroll
        for (int r = 0; r < 2; ++r) {
            int idx = r * 256 + tid;
            int row = idx >> 2, ch = idx & 3;
            int gr = row0 + row; if (gr > N - 1) gr = N - 1;
            *(half8*)&As[row * LP + ch * 8] = *(const half8*)(G + (size_t)gr * 512 + k0 + ch * 8);
        }
        {
            int row = tid >> 2, ch = tid & 3;
            *(half8*)&Bs[row * LP + ch * 8] = *(const half8*)(VT + (size_t)row * 512 + k0 + ch * 8);
        }
        __syncthreads();
        half8 af[2], bf[4];
        #pragma unroll
        for (int i = 0; i < 2; ++i)
            af[i] = *(const half8*)&As[(m_base + i * 16 + l15) * LP + quad * 8];
        #pragma unroll
        for (int j = 0; j < 4; ++j)
            bf[j] = *(const half8*)&Bs[(j * 16 + l15) * LP + quad * 8];
        #pragma unroll
        for (int i = 0; i < 2; ++i)
            #pragma unroll
            for (int j = 0; j < 4; ++j)
                acc[i][j] = __builtin_amdgcn_mfma_f32_16x16x32_f16(af[i], bf[j], acc[i][j], 0, 0, 0);
        __syncthreads();
    }

    #pragma unroll
    for (int i = 0; i < 2; ++i) {
        #pragma unroll
        for (int j = 0; j < 4; ++j) {
            int col = j * 16 + l15;
            float c1 = Vext[col], c2 = Vext[64 + col], c3 = Vext[128 + col];
            #pragma unroll
            for (int r = 0; r < 4; ++r) {
                int row = row0 + m_base + i * 16 + quad * 4 + r;
                if (row < N)
                    out[(size_t)row * 64 + col] =
                        acc[i][j][r] + c1 + dvec[row] * c2 + Advec[row] * c3;
            }
        }
    }
}

extern "C" void kernel_launch(void* const* d_in, const int* in_sizes, int n_in,
                              void* d_out, int out_size, void* d_ws, size_t ws_size,
                              hipStream_t stream) {
    const float* x    = (const float*)d_in[0];
    const int*   esrc = (const int*)d_in[1];
    const int*   edst = (const int*)d_in[2];
    const float* W0s  = (const float*)d_in[3];
    const float* W0n  = (const float*)d_in[4];
    const float* b0   = (const float*)d_in[5];
    const float* W1s  = (const float*)d_in[6];
    const float* W1n  = (const float*)d_in[7];
    const float* b1   = (const float*)d_in[8];
    const float* W2s  = (const float*)d_in[9];
    const float* W2n  = (const float*)d_in[10];
    const float* b2   = (const float*)d_in[11];
    const float* Wfc  = (const float*)d_in[12];
    const float* bfc  = (const float*)d_in[13];
    float* out = (float*)d_out;

    // ---- workspace layout ----
    _Float16* G    = (_Float16*)d_ws;                 // NN x 512: [X | AX | A2X | A3X]
    _Float16* VT16 = G + (size_t)NN * 512;            // 64 x 512
    float* Ca      = (float*)(VT16 + 64 * 512);       // 515 x 256
    float* Cb      = Ca + CROWS * 256;                // 515 x 256
    float* Cs      = Cb + CROWS * 256;                // 515 x 256 (shift scratch)
    float* Vf      = Cs + CROWS * 256;                // 515 x 64
    float* dinv    = Vf + CROWS * 64;                 // NN
    float* dvec    = dinv + NN;                       // NN
    float* Advec   = dvec + NN;                       // NN
    int* cnt       = (int*)(Advec + NN);              // NN
    int* offs      = cnt + NN;                        // NN+1
    int* cursor    = offs + NN + 1;                   // NN
    int* csr_src   = cursor + NN;                     // NE
    int* blockSums = csr_src + NE;                    // SCAN_BLOCKS

    // ---- CSR build ----
    hipMemsetAsync(cnt, 0, (size_t)NN * sizeof(int), stream);
    hipMemsetAsync(cursor, 0, (size_t)NN * sizeof(int), stream);
    hist_count<<<(NE + 255) / 256, 256, 0, stream>>>(edst, cnt, NE);
    scan_block_sums<<<SCAN_BLOCKS, 256, 0, stream>>>(cnt, blockSums, NN);
    scan_top<<<1, 256, 0, stream>>>(blockSums, SCAN_BLOCKS);
    scan_final<<<SCAN_BLOCKS, 256, 0, stream>>>(cnt, blockSums, offs, NN);
    make_dinv<<<(NN + 255) / 256, 256, 0, stream>>>(cnt, dinv, dvec, NN);
    csr_place<<<(NE + 255) / 256, 256, 0, stream>>>(esrc, edst, offs, cursor, csr_src, NE);

    // ---- weight-chain composition (fp32, tiny) ----
    const int cg = (CROWS * 256 + 255) / 256;
    const int gR = (CROWS + 63) / 64;   // 9
    init_C1<<<cg, 256, 0, stream>>>(W0s, W0n, b0, Ca);
    // layer 1: Cb = Ca @ W1s + shiftA(Ca) @ W1n ; row512 += b1
    shift_copy<<<cg, 256, 0, stream>>>(Ca, Cs);
    gemm_fused32<<<dim3(gR, 4), 256, 0, stream>>>(Ca, Cs, W1s, W1n, nullptr, Cb, CROWS, 256, 256);
    add_row<<<1, 256, 0, stream>>>(Cb + 512 * 256, b1, 256);
    // layer 2: Ca = Cb @ W2s + shiftA(Cb) @ W2n ; row512 += b2
    shift_copy<<<cg, 256, 0, stream>>>(Cb, Cs);
    gemm_fused32<<<dim3(gR, 4), 256, 0, stream>>>(Cb, Cs, W2s, W2n, nullptr, Ca, CROWS, 256, 256);
    add_row<<<1, 256, 0, stream>>>(Ca + 512 * 256, b2, 256);
    // fc: Vf = Ca @ Wfc ; row512 += bfc
    gemm_fused32<<<dim3(gR, 1), 256, 0, stream>>>(Ca, nullptr, Wfc, nullptr, nullptr, Vf, CROWS, 256, 64);
    add_row<<<1, 64, 0, stream>>>(Vf + 512 * 64, bfc, 64);
    vt_convert<<<(64 * 512 + 255) / 256, 256, 0, stream>>>(Vf, VT16);

    // ---- X powers: G = [X16 | AX | A2X | A3X] ----
    convert_x<<<(NN * (F_IN / 4) + 255) / 256, 256, 0, stream>>>(x, G, NN);
    const int ggrid = (NN + 15) / 16;
    gather128<<<ggrid, 256, 0, stream>>>(G, 0,   128, csr_src, offs, dinv, G, NN);
    gather128<<<ggrid, 256, 0, stream>>>(G, 128, 256, csr_src, offs, dinv, G, NN);
    gather128<<<ggrid, 256, 0, stream>>>(G, 256, 384, csr_src, offs, dinv, G, NN);
    compute_Ad<<<(NN + 255) / 256, 256, 0, stream>>>(dvec, dinv, csr_src, offs, Advec, NN);

    // ---- final GEMM ----
    gemm_final<<<(NN + 127) / 128, 256, 0, stream>>>(
        G, VT16, Vf + 512 * 64, dvec, Advec, out, NN);
}

// Round 5
// 326.828 us; speedup vs baseline: 22.5450x; 1.2582x over previous
//
#include <hip/hip_runtime.h>

#define NN 50000
#define NE 800000
#define F_IN 128
#define HID 256
#define N_CLS 64
#define SCAN_BLOCKS ((NN + 255) / 256)   // 196
#define CROWS 515                        // basis: X,AX,A2X,A3X (4*128) + 1,d,Ad

typedef _Float16 half8 __attribute__((ext_vector_type(8)));
typedef float f32x4 __attribute__((ext_vector_type(4)));

// ================= CSR build =================
__global__ void hist_count(const int* __restrict__ dst, int* __restrict__ cnt, int E) {
    int i = blockIdx.x * blockDim.x + threadIdx.x;
    if (i < E) atomicAdd(&cnt[dst[i]], 1);
}

__global__ void scan_block_sums(const int* __restrict__ cnt, int* __restrict__ blockSums, int n) {
    __shared__ int s[256];
    int t = threadIdx.x;
    int i = blockIdx.x * 256 + t;
    s[t] = (i < n) ? cnt[i] : 0;
    __syncthreads();
    for (int off = 128; off > 0; off >>= 1) {
        if (t < off) s[t] += s[t + off];
        __syncthreads();
    }
    if (t == 0) blockSums[blockIdx.x] = s[0];
}

__global__ void scan_top(int* __restrict__ blockSums, int nb) {
    __shared__ int s[256];
    int t = threadIdx.x;
    s[t] = (t < nb) ? blockSums[t] : 0;
    __syncthreads();
    for (int off = 1; off < 256; off <<= 1) {
        int v = (t >= off) ? s[t - off] : 0;
        __syncthreads();
        s[t] += v;
        __syncthreads();
    }
    if (t < nb) blockSums[t] = (t > 0) ? s[t - 1] : 0;  // exclusive
}

// offs + cursor seed + dinv, fused
__global__ void scan_final(const int* __restrict__ cnt, const int* __restrict__ blockBase,
                           int* __restrict__ offs, int* __restrict__ cursor,
                           float* __restrict__ dinv, int n) {
    __shared__ int s[256];
    int t = threadIdx.x;
    int i = blockIdx.x * 256 + t;
    int v = (i < n) ? cnt[i] : 0;
    s[t] = v;
    __syncthreads();
    for (int off = 1; off < 256; off <<= 1) {
        int u = (t >= off) ? s[t - off] : 0;
        __syncthreads();
        s[t] += u;
        __syncthreads();
    }
    if (i < n) {
        int o = blockBase[blockIdx.x] + s[t] - v;
        offs[i] = o;
        cursor[i] = o;
        dinv[i] = 1.0f / (float)max(v, 1);
    }
    if (i == n - 1) offs[n] = blockBase[blockIdx.x] + s[t];
}

// cursor pre-seeded with offs -> slot is absolute; csr entries are ushort
__global__ void csr_place(const int* __restrict__ src, const int* __restrict__ dst,
                          int* __restrict__ cursor, unsigned short* __restrict__ csr, int E) {
    int e = blockIdx.x * blockDim.x + threadIdx.x;
    if (e < E) {
        int slot = atomicAdd(&cursor[dst[e]], 1);
        csr[slot] = (unsigned short)src[e];
    }
}

// ================= affine-map composition (515-row coefficient matrices) =================
// C1 rows: [0,128)=W0s, [128,256)=W0n, 512=b0, else 0.
__global__ void init_C1(const float* __restrict__ W0s, const float* __restrict__ W0n,
                        const float* __restrict__ b0, float* __restrict__ C) {
    int idx = blockIdx.x * blockDim.x + threadIdx.x;
    if (idx >= CROWS * 256) return;
    int r = idx / 256, m = idx % 256;
    float v = 0.0f;
    if (r < 128) v = W0s[r * 256 + m];
    else if (r < 256) v = W0n[(r - 128) * 256 + m];
    else if (r == 512) v = b0[m];
    C[idx] = v;
}

// C[N,M] = A @ B1 (+ shiftA(A) @ B2 if SHIFT) ; brow added to global row 512 only.
// shiftA row map: r in [128,512) <- r-128 ; 513 <- 512 ; 514 <- 513 ; else zero.
template <bool SHIFT>
__global__ __launch_bounds__(256) void gemm_compose(
    const float* __restrict__ A,
    const float* __restrict__ B1, const float* __restrict__ B2,
    const float* __restrict__ brow, float* __restrict__ C,
    int N, int K, int M)
{
    __shared__ float As[64][17];
    __shared__ float Bs[16][64];

    const int tid = threadIdx.x;
    const int tx = tid & 15, ty = tid >> 4;
    const int row0 = blockIdx.x * 64;
    const int col0 = blockIdx.y * 64;

    const int lr = tid >> 2;
    const int lc = tid & 3;
    const int br = tid >> 4;
    const int bc = tid & 15;

    float acc[4][4] = {};
    const int npass = SHIFT ? 2 : 1;

    for (int pass = 0; pass < npass; ++pass) {
        const float* B = pass ? B2 : B1;
        int grow = row0 + lr;                 // output row this thread stages
        int p;                                // source row in A
        if (pass == 0) p = (grow < N) ? grow : -1;
        else p = (grow >= 128 && grow < 512) ? grow - 128
               : (grow == 513) ? 512 : (grow == 514) ? 513 : -1;

        for (int k0 = 0; k0 < K; k0 += 16) {
            float4 av = make_float4(0.f, 0.f, 0.f, 0.f);
            if (p >= 0)
                av = *(const float4*)(A + (size_t)p * K + k0 + lc * 4);
            As[lr][lc * 4 + 0] = av.x;
            As[lr][lc * 4 + 1] = av.y;
            As[lr][lc * 4 + 2] = av.z;
            As[lr][lc * 4 + 3] = av.w;

            *(float4*)&Bs[br][bc * 4] =
                *(const float4*)(B + (size_t)(k0 + br) * M + col0 + bc * 4);

            __syncthreads();
            #pragma unroll
            for (int k = 0; k < 16; ++k) {
                float a[4];
                #pragma unroll
                for (int i = 0; i < 4; ++i) a[i] = As[ty * 4 + i][k];
                float4 bv = *(const float4*)&Bs[k][tx * 4];
                const float b[4] = {bv.x, bv.y, bv.z, bv.w};
                #pragma unroll
                for (int i = 0; i < 4; ++i)
                    #pragma unroll
                    for (int j = 0; j < 4; ++j)
                        acc[i][j] += a[i] * b[j];
            }
            __syncthreads();
        }
    }

    #pragma unroll
    for (int i = 0; i < 4; ++i) {
        int r = row0 + ty * 4 + i;
        if (r < N) {
            #pragma unroll
            for (int j = 0; j < 4; ++j) {
                float v = acc[i][j];
                if (brow && r == 512) v += brow[col0 + tx * 4 + j];
                C[(size_t)r * M + col0 + tx * 4 + j] = v;
            }
        }
    }
}

// Vf fp32 [515][64] -> BT fp16 [256][128]: BT[k*64+c][r] = Vf[(k*128+r)*64+c]
__global__ void vt_convert(const float* __restrict__ Vf, _Float16* __restrict__ BT) {
    int idx = blockIdx.x * blockDim.x + threadIdx.x;
    if (idx >= 256 * 128) return;
    int m = idx / 128, r = idx % 128;
    int k = m >> 6, c = m & 63;
    BT[idx] = (_Float16)Vf[(size_t)(k * 128 + r) * 64 + c];
}

// ================= Y GEMM: Y[N][256] = X(fp32)[N][128] @ BT^T, fp16 out =================
__global__ __launch_bounds__(256) void gemm_Y(
    const float* __restrict__ X, const _Float16* __restrict__ BT,
    _Float16* __restrict__ Y, int N)
{
    constexpr int LP = 40;
    __shared__ _Float16 As[128 * LP];
    __shared__ _Float16 Bs[128 * LP];

    const int tid = threadIdx.x;
    const int wave = tid >> 6;
    const int lane = tid & 63;
    const int l15 = lane & 15;
    const int quad = lane >> 4;
    const int wrow = wave >> 1;           // 2 waves along M
    const int wcol = wave & 1;            // 2 waves along N
    const int m_base = wrow * 64;
    const int n_base = wcol * 64;

    const int row0 = blockIdx.x * 128;
    const int col0 = blockIdx.y * 128;

    f32x4 acc[4][4] = {};

    for (int k0 = 0; k0 < 128; k0 += 32) {
        // stage A from fp32 X: 128 rows x 32 halves
        #pragma unroll
        for (int r = 0; r < 2; ++r) {
            int idx = r * 256 + tid;
            int row = idx >> 2, ch = idx & 3;
            int gr = row0 + row; if (gr > N - 1) gr = N - 1;
            const float* ap = X + (size_t)gr * 128 + k0 + ch * 8;
            float4 f0 = *(const float4*)ap;
            float4 f1 = *(const float4*)(ap + 4);
            half8 v = { (_Float16)f0.x, (_Float16)f0.y, (_Float16)f0.z, (_Float16)f0.w,
                        (_Float16)f1.x, (_Float16)f1.y, (_Float16)f1.z, (_Float16)f1.w };
            *(half8*)&As[row * LP + ch * 8] = v;
        }
        // stage B: BT rows (col0..col0+127) x 32 halves, K=128
        #pragma unroll
        for (int r = 0; r < 2; ++r) {
            int idx = r * 256 + tid;
            int row = idx >> 2, ch = idx & 3;
            *(half8*)&Bs[row * LP + ch * 8] =
                *(const half8*)(BT + (size_t)(col0 + row) * 128 + k0 + ch * 8);
        }
        __syncthreads();
        half8 af[4], bf[4];
        #pragma unroll
        for (int i = 0; i < 4; ++i)
            af[i] = *(const half8*)&As[(m_base + i * 16 + l15) * LP + quad * 8];
        #pragma unroll
        for (int j = 0; j < 4; ++j)
            bf[j] = *(const half8*)&Bs[(n_base + j * 16 + l15) * LP + quad * 8];
        #pragma unroll
        for (int i = 0; i < 4; ++i)
            #pragma unroll
            for (int j = 0; j < 4; ++j)
                acc[i][j] = __builtin_amdgcn_mfma_f32_16x16x32_f16(af[i], bf[j], acc[i][j], 0, 0, 0);
        __syncthreads();
    }

    // epilogue: col=lane&15, row=quad*4+reg
    #pragma unroll
    for (int i = 0; i < 4; ++i) {
        #pragma unroll
        for (int j = 0; j < 4; ++j) {
            int col = col0 + n_base + j * 16 + l15;
            #pragma unroll
            for (int r = 0; r < 4; ++r) {
                int row = row0 + m_base + i * 16 + quad * 4 + r;
                if (row < N)
                    Y[(size_t)row * 256 + col] = (_Float16)acc[i][j][r];
            }
        }
    }
}

// ================= output-side gather chain =================
// Tout[node] = Yadd[node] + cvec + dinv[node] * sum_e Tin[csr[e]]
// 8 lanes per node, half8 per lane (64-wide rows).
template <bool OUT_F32>
__global__ __launch_bounds__(256) void gather64(
    const _Float16* __restrict__ Tin, int sin,
    const unsigned short* __restrict__ csr, const int* __restrict__ offs,
    const float* __restrict__ dinv,
    const _Float16* __restrict__ Yadd,   // stride 256, pre-offset to column block
    const float* __restrict__ cvec,      // 64 floats
    void* __restrict__ Tout, int N)
{
    int node = blockIdx.x * 32 + (threadIdx.x >> 3);
    int lane = threadIdx.x & 7;
    if (node >= N) return;
    int beg = offs[node], end = offs[node + 1];
    float acc[8] = {};
    int e = beg;
    for (; e + 3 < end; e += 4) {
        int s0 = csr[e], s1 = csr[e + 1], s2 = csr[e + 2], s3 = csr[e + 3];
        half8 v0 = *(const half8*)(Tin + (size_t)s0 * sin + lane * 8);
        half8 v1 = *(const half8*)(Tin + (size_t)s1 * sin + lane * 8);
        half8 v2 = *(const half8*)(Tin + (size_t)s2 * sin + lane * 8);
        half8 v3 = *(const half8*)(Tin + (size_t)s3 * sin + lane * 8);
        #pragma unroll
        for (int j = 0; j < 8; ++j)
            acc[j] += ((float)v0[j] + (float)v1[j]) + ((float)v2[j] + (float)v3[j]);
    }
    for (; e < end; ++e) {
        half8 v = *(const half8*)(Tin + (size_t)csr[e] * sin + lane * 8);
        #pragma unroll
        for (int j = 0; j < 8; ++j) acc[j] += (float)v[j];
    }
    float sc = dinv[node];
    half8 y = *(const half8*)(Yadd + (size_t)node * 256 + lane * 8);
    if (OUT_F32) {
        float* o = (float*)Tout + (size_t)node * 64 + lane * 8;
        float4 o0, o1;
        o0.x = acc[0] * sc + (float)y[0] + cvec[lane * 8 + 0];
        o0.y = acc[1] * sc + (float)y[1] + cvec[lane * 8 + 1];
        o0.z = acc[2] * sc + (float)y[2] + cvec[lane * 8 + 2];
        o0.w = acc[3] * sc + (float)y[3] + cvec[lane * 8 + 3];
        o1.x = acc[4] * sc + (float)y[4] + cvec[lane * 8 + 4];
        o1.y = acc[5] * sc + (float)y[5] + cvec[lane * 8 + 5];
        o1.z = acc[6] * sc + (float)y[6] + cvec[lane * 8 + 6];
        o1.w = acc[7] * sc + (float)y[7] + cvec[lane * 8 + 7];
        *(float4*)o = o0;
        *(float4*)(o + 4) = o1;
    } else {
        half8 o;
        #pragma unroll
        for (int j = 0; j < 8; ++j)
            o[j] = (_Float16)(acc[j] * sc + (float)y[j] + cvec[lane * 8 + j]);
        *(half8*)((_Float16*)Tout + (size_t)node * 64 + lane * 8) = o;
    }
}

extern "C" void kernel_launch(void* const* d_in, const int* in_sizes, int n_in,
                              void* d_out, int out_size, void* d_ws, size_t ws_size,
                              hipStream_t stream) {
    const float* x    = (const float*)d_in[0];
    const int*   esrc = (const int*)d_in[1];
    const int*   edst = (const int*)d_in[2];
    const float* W0s  = (const float*)d_in[3];
    const float* W0n  = (const float*)d_in[4];
    const float* b0   = (const float*)d_in[5];
    const float* W1s  = (const float*)d_in[6];
    const float* W1n  = (const float*)d_in[7];
    const float* b1   = (const float*)d_in[8];
    const float* W2s  = (const float*)d_in[9];
    const float* W2n  = (const float*)d_in[10];
    const float* b2   = (const float*)d_in[11];
    const float* Wfc  = (const float*)d_in[12];
    const float* bfc  = (const float*)d_in[13];
    float* out = (float*)d_out;

    // ---- workspace layout ----
    _Float16* Y   = (_Float16*)d_ws;                  // N x 256  [Y0|Y1|Y2|Y3]
    _Float16* Ta  = Y + (size_t)NN * 256;             // N x 64
    _Float16* Tb  = Ta + (size_t)NN * 64;             // N x 64
    _Float16* BT  = Tb + (size_t)NN * 64;             // 256 x 128
    float* Ca     = (float*)(BT + 256 * 128);         // 515 x 256
    float* Cb     = Ca + CROWS * 256;                 // 515 x 256
    float* Vf     = Cb + CROWS * 256;                 // 515 x 64
    float* dinv   = Vf + CROWS * 64;                  // N
    int* cnt      = (int*)(dinv + NN);                // N
    int* offs     = cnt + NN;                         // N+1
    int* cursor   = offs + NN + 1;                    // N
    int* blockSums = cursor + NN;                     // SCAN_BLOCKS
    unsigned short* csr = (unsigned short*)(blockSums + SCAN_BLOCKS);  // E

    // ---- CSR build ----
    hipMemsetAsync(cnt, 0, (size_t)NN * sizeof(int), stream);
    hist_count<<<(NE + 255) / 256, 256, 0, stream>>>(edst, cnt, NE);
    scan_block_sums<<<SCAN_BLOCKS, 256, 0, stream>>>(cnt, blockSums, NN);
    scan_top<<<1, 256, 0, stream>>>(blockSums, SCAN_BLOCKS);
    scan_final<<<SCAN_BLOCKS, 256, 0, stream>>>(cnt, blockSums, offs, cursor, dinv, NN);
    csr_place<<<(NE + 255) / 256, 256, 0, stream>>>(esrc, edst, cursor, csr, NE);

    // ---- weight-chain composition (fp32, tiny) ----
    const int cg = (CROWS * 256 + 255) / 256;
    const int gR = (CROWS + 63) / 64;   // 9
    init_C1<<<cg, 256, 0, stream>>>(W0s, W0n, b0, Ca);
    gemm_compose<true><<<dim3(gR, 4), 256, 0, stream>>>(Ca, W1s, W1n, b1, Cb, CROWS, 256, 256);
    gemm_compose<true><<<dim3(gR, 4), 256, 0, stream>>>(Cb, W2s, W2n, b2, Ca, CROWS, 256, 256);
    gemm_compose<false><<<dim3(gR, 1), 256, 0, stream>>>(Ca, Wfc, nullptr, bfc, Vf, CROWS, 256, 64);
    vt_convert<<<(256 * 128 + 255) / 256, 256, 0, stream>>>(Vf, BT);

    // ---- Y = X @ [V0|V1|V2|V3] ----
    gemm_Y<<<dim3((NN + 127) / 128, 2), 256, 0, stream>>>(x, BT, Y, NN);

    // ---- output-side propagation: out = Y0 + c1 + A(Y1 + c2 + A(Y2 + c3 + A*Y3)) ----
    const int ggrid = (NN + 31) / 32;
    gather64<false><<<ggrid, 256, 0, stream>>>(
        Y + 192, 256, csr, offs, dinv, Y + 128, Vf + (size_t)514 * 64, Ta, NN);
    gather64<false><<<ggrid, 256, 0, stream>>>(
        Ta, 64, csr, offs, dinv, Y + 64, Vf + (size_t)513 * 64, Tb, NN);
    gather64<true><<<ggrid, 256, 0, stream>>>(
        Tb, 64, csr, offs, dinv, Y, Vf + (size_t)512 * 64, out, NN);
}

// Round 6
// 301.544 us; speedup vs baseline: 24.4353x; 1.0838x over previous
//
#include <hip/hip_runtime.h>

#define NN 50000
#define NE 800000
#define F_IN 128
#define HID 256
#define N_CLS 64
#define SCAN_BLOCKS ((NN + 255) / 256)   // 196
#define CROWS 515                        // basis: X,AX,A2X,A3X (4*128) + 1,d,Ad

typedef _Float16 half8 __attribute__((ext_vector_type(8)));
typedef float f32x4 __attribute__((ext_vector_type(4)));

// ================= CSR build =================
// rank[e] = position of edge e within its dst bucket (the hist atomic's old value)
__global__ void hist_count(const int* __restrict__ dst, int* __restrict__ cnt,
                           int* __restrict__ rank, int E) {
    int i = blockIdx.x * blockDim.x + threadIdx.x;
    if (i < E) rank[i] = atomicAdd(&cnt[dst[i]], 1);
}

__global__ void scan_block_sums(const int* __restrict__ cnt, int* __restrict__ blockSums, int n) {
    __shared__ int s[256];
    int t = threadIdx.x;
    int i = blockIdx.x * 256 + t;
    s[t] = (i < n) ? cnt[i] : 0;
    __syncthreads();
    for (int off = 128; off > 0; off >>= 1) {
        if (t < off) s[t] += s[t + off];
        __syncthreads();
    }
    if (t == 0) blockSums[blockIdx.x] = s[0];
}

__global__ void scan_top(int* __restrict__ blockSums, int nb) {
    __shared__ int s[256];
    int t = threadIdx.x;
    s[t] = (t < nb) ? blockSums[t] : 0;
    __syncthreads();
    for (int off = 1; off < 256; off <<= 1) {
        int v = (t >= off) ? s[t - off] : 0;
        __syncthreads();
        s[t] += v;
        __syncthreads();
    }
    if (t < nb) blockSums[t] = (t > 0) ? s[t - 1] : 0;  // exclusive
}

// offs + dinv, fused
__global__ void scan_final(const int* __restrict__ cnt, const int* __restrict__ blockBase,
                           int* __restrict__ offs, float* __restrict__ dinv, int n) {
    __shared__ int s[256];
    int t = threadIdx.x;
    int i = blockIdx.x * 256 + t;
    int v = (i < n) ? cnt[i] : 0;
    s[t] = v;
    __syncthreads();
    for (int off = 1; off < 256; off <<= 1) {
        int u = (t >= off) ? s[t - off] : 0;
        __syncthreads();
        s[t] += u;
        __syncthreads();
    }
    if (i < n) {
        offs[i] = blockBase[blockIdx.x] + s[t] - v;
        dinv[i] = 1.0f / (float)max(v, 1);
    }
    if (i == n - 1) offs[n] = blockBase[blockIdx.x] + s[t];
}

// atomic-free placement: slot fully determined by offs + rank
__global__ void csr_place2(const int* __restrict__ src, const int* __restrict__ dst,
                           const int* __restrict__ rank, const int* __restrict__ offs,
                           unsigned short* __restrict__ csr, int E) {
    int e = blockIdx.x * blockDim.x + threadIdx.x;
    if (e < E) csr[offs[dst[e]] + rank[e]] = (unsigned short)src[e];
}

// ================= affine-map composition =================
// virtual C1 row pointer: r<128 -> W0s[r], r<256 -> W0n[r-128], r==512 -> b0, else zero
__device__ __forceinline__ const float* virtC1_row(int r, const float* W0s,
                                                   const float* W0n, const float* b0) {
    if (r < 0) return nullptr;
    if (r < 128) return W0s + (size_t)r * 256;
    if (r < 256) return W0n + (size_t)(r - 128) * 256;
    if (r == 512) return b0;
    return nullptr;
}

// shiftA source-row map: r in [128,512) <- r-128 ; 513 <- 512 ; 514 <- 513 ; else -1
__device__ __forceinline__ int shift_src(int r) {
    if (r >= 128 && r < 512) return r - 128;
    if (r == 513) return 512;
    if (r == 514) return 513;
    return -1;
}

// layer-1 compose: C = virtC1 @ W1s + shiftA(virtC1) @ W1n ; row 512 += b1. K=M=256.
__global__ __launch_bounds__(256) void gemm_compose_first(
    const float* __restrict__ W0s, const float* __restrict__ W0n, const float* __restrict__ b0,
    const float* __restrict__ B1, const float* __restrict__ B2,
    const float* __restrict__ brow, float* __restrict__ C)
{
    __shared__ float As[64][17];
    __shared__ float Bs[16][64];
    const int tid = threadIdx.x;
    const int tx = tid & 15, ty = tid >> 4;
    const int row0 = blockIdx.x * 64;
    const int col0 = blockIdx.y * 64;
    const int lr = tid >> 2, lc = tid & 3;
    const int br = tid >> 4, bc = tid & 15;

    float acc[4][4] = {};

    for (int pass = 0; pass < 2; ++pass) {
        const float* B = pass ? B2 : B1;
        int grow = row0 + lr;
        int srcr = pass ? shift_src(grow) : (grow < CROWS ? grow : -1);
        const float* ap = virtC1_row(srcr, W0s, W0n, b0);

        for (int k0 = 0; k0 < 256; k0 += 16) {
            float4 av = make_float4(0.f, 0.f, 0.f, 0.f);
            if (ap) av = *(const float4*)(ap + k0 + lc * 4);
            As[lr][lc * 4 + 0] = av.x;
            As[lr][lc * 4 + 1] = av.y;
            As[lr][lc * 4 + 2] = av.z;
            As[lr][lc * 4 + 3] = av.w;
            *(float4*)&Bs[br][bc * 4] = *(const float4*)(B + (size_t)(k0 + br) * 256 + col0 + bc * 4);
            __syncthreads();
            #pragma unroll
            for (int k = 0; k < 16; ++k) {
                float a[4];
                #pragma unroll
                for (int i = 0; i < 4; ++i) a[i] = As[ty * 4 + i][k];
                float4 bv = *(const float4*)&Bs[k][tx * 4];
                const float b[4] = {bv.x, bv.y, bv.z, bv.w};
                #pragma unroll
                for (int i = 0; i < 4; ++i)
                    #pragma unroll
                    for (int j = 0; j < 4; ++j)
                        acc[i][j] += a[i] * b[j];
            }
            __syncthreads();
        }
    }

    #pragma unroll
    for (int i = 0; i < 4; ++i) {
        int r = row0 + ty * 4 + i;
        if (r < CROWS) {
            #pragma unroll
            for (int j = 0; j < 4; ++j) {
                float v = acc[i][j];
                if (r == 512) v += brow[col0 + tx * 4 + j];
                C[(size_t)r * 256 + col0 + tx * 4 + j] = v;
            }
        }
    }
}

// middle compose: C = A @ B1 + shiftA(A) @ B2 ; row 512 += b. K=M=256.
__global__ __launch_bounds__(256) void gemm_compose_mid(
    const float* __restrict__ A,
    const float* __restrict__ B1, const float* __restrict__ B2,
    const float* __restrict__ brow, float* __restrict__ C)
{
    __shared__ float As[64][17];
    __shared__ float Bs[16][64];
    const int tid = threadIdx.x;
    const int tx = tid & 15, ty = tid >> 4;
    const int row0 = blockIdx.x * 64;
    const int col0 = blockIdx.y * 64;
    const int lr = tid >> 2, lc = tid & 3;
    const int br = tid >> 4, bc = tid & 15;

    float acc[4][4] = {};

    for (int pass = 0; pass < 2; ++pass) {
        const float* B = pass ? B2 : B1;
        int grow = row0 + lr;
        int p = pass ? shift_src(grow) : (grow < CROWS ? grow : -1);

        for (int k0 = 0; k0 < 256; k0 += 16) {
            float4 av = make_float4(0.f, 0.f, 0.f, 0.f);
            if (p >= 0) av = *(const float4*)(A + (size_t)p * 256 + k0 + lc * 4);
            As[lr][lc * 4 + 0] = av.x;
            As[lr][lc * 4 + 1] = av.y;
            As[lr][lc * 4 + 2] = av.z;
            As[lr][lc * 4 + 3] = av.w;
            *(float4*)&Bs[br][bc * 4] = *(const float4*)(B + (size_t)(k0 + br) * 256 + col0 + bc * 4);
            __syncthreads();
            #pragma unroll
            for (int k = 0; k < 16; ++k) {
                float a[4];
                #pragma unroll
                for (int i = 0; i < 4; ++i) a[i] = As[ty * 4 + i][k];
                float4 bv = *(const float4*)&Bs[k][tx * 4];
                const float b[4] = {bv.x, bv.y, bv.z, bv.w};
                #pragma unroll
                for (int i = 0; i < 4; ++i)
                    #pragma unroll
                    for (int j = 0; j < 4; ++j)
                        acc[i][j] += a[i] * b[j];
            }
            __syncthreads();
        }
    }

    #pragma unroll
    for (int i = 0; i < 4; ++i) {
        int r = row0 + ty * 4 + i;
        if (r < CROWS) {
            #pragma unroll
            for (int j = 0; j < 4; ++j) {
                float v = acc[i][j];
                if (r == 512) v += brow[col0 + tx * 4 + j];
                C[(size_t)r * 256 + col0 + tx * 4 + j] = v;
            }
        }
    }
}

// final compose: Vf[515][64] = A @ Wfc ; row 512 += bfc. Also emits BT fp16 [256][128]:
// BT[((r>>7)*64 + c)*128 + (r&127)] = Vf[r][c] for r<512.
__global__ __launch_bounds__(256) void gemm_compose_last(
    const float* __restrict__ A, const float* __restrict__ B1,
    const float* __restrict__ brow, float* __restrict__ Vf, _Float16* __restrict__ BT)
{
    __shared__ float As[64][17];
    __shared__ float Bs[16][64];
    const int tid = threadIdx.x;
    const int tx = tid & 15, ty = tid >> 4;
    const int row0 = blockIdx.x * 64;
    const int lr = tid >> 2, lc = tid & 3;
    const int br = tid >> 4, bc = tid & 15;

    float acc[4][4] = {};

    for (int k0 = 0; k0 < 256; k0 += 16) {
        float4 av = make_float4(0.f, 0.f, 0.f, 0.f);
        int grow = row0 + lr;
        if (grow < CROWS) av = *(const float4*)(A + (size_t)grow * 256 + k0 + lc * 4);
        As[lr][lc * 4 + 0] = av.x;
        As[lr][lc * 4 + 1] = av.y;
        As[lr][lc * 4 + 2] = av.z;
        As[lr][lc * 4 + 3] = av.w;
        *(float4*)&Bs[br][bc * 4] = *(const float4*)(B1 + (size_t)(k0 + br) * 64 + bc * 4);
        __syncthreads();
        #pragma unroll
        for (int k = 0; k < 16; ++k) {
            float a[4];
            #pragma unroll
            for (int i = 0; i < 4; ++i) a[i] = As[ty * 4 + i][k];
            float4 bv = *(const float4*)&Bs[k][tx * 4];
            const float b[4] = {bv.x, bv.y, bv.z, bv.w};
            #pragma unroll
            for (int i = 0; i < 4; ++i)
                #pragma unroll
                for (int j = 0; j < 4; ++j)
                    acc[i][j] += a[i] * b[j];
        }
        __syncthreads();
    }

    #pragma unroll
    for (int i = 0; i < 4; ++i) {
        int r = row0 + ty * 4 + i;
        if (r < CROWS) {
            #pragma unroll
            for (int j = 0; j < 4; ++j) {
                int c = tx * 4 + j;
                float v = acc[i][j];
                if (r == 512) v += brow[c];
                Vf[(size_t)r * 64 + c] = v;
                if (r < 512)
                    BT[(size_t)((r >> 7) * 64 + c) * 128 + (r & 127)] = (_Float16)v;
            }
        }
    }
}

// ================= Y GEMM: Y[N][256] = X(fp32)[N][128] @ BT^T, fp16 out =================
__global__ __launch_bounds__(256) void gemm_Y(
    const float* __restrict__ X, const _Float16* __restrict__ BT,
    _Float16* __restrict__ Y, int N)
{
    constexpr int LP = 40;
    __shared__ _Float16 As[128 * LP];
    __shared__ _Float16 Bs[128 * LP];

    const int tid = threadIdx.x;
    const int wave = tid >> 6;
    const int lane = tid & 63;
    const int l15 = lane & 15;
    const int quad = lane >> 4;
    const int wrow = wave >> 1;
    const int wcol = wave & 1;
    const int m_base = wrow * 64;
    const int n_base = wcol * 64;

    const int row0 = blockIdx.x * 128;
    const int col0 = blockIdx.y * 128;

    f32x4 acc[4][4] = {};

    for (int k0 = 0; k0 < 128; k0 += 32) {
        #pragma unroll
        for (int r = 0; r < 2; ++r) {
            int idx = r * 256 + tid;
            int row = idx >> 2, ch = idx & 3;
            int gr = row0 + row; if (gr > N - 1) gr = N - 1;
            const float* ap = X + (size_t)gr * 128 + k0 + ch * 8;
            float4 f0 = *(const float4*)ap;
            float4 f1 = *(const float4*)(ap + 4);
            half8 v = { (_Float16)f0.x, (_Float16)f0.y, (_Float16)f0.z, (_Float16)f0.w,
                        (_Float16)f1.x, (_Float16)f1.y, (_Float16)f1.z, (_Float16)f1.w };
            *(half8*)&As[row * LP + ch * 8] = v;
        }
        #pragma unroll
        for (int r = 0; r < 2; ++r) {
            int idx = r * 256 + tid;
            int row = idx >> 2, ch = idx & 3;
            *(half8*)&Bs[row * LP + ch * 8] =
                *(const half8*)(BT + (size_t)(col0 + row) * 128 + k0 + ch * 8);
        }
        __syncthreads();
        half8 af[4], bf[4];
        #pragma unroll
        for (int i = 0; i < 4; ++i)
            af[i] = *(const half8*)&As[(m_base + i * 16 + l15) * LP + quad * 8];
        #pragma unroll
        for (int j = 0; j < 4; ++j)
            bf[j] = *(const half8*)&Bs[(n_base + j * 16 + l15) * LP + quad * 8];
        #pragma unroll
        for (int i = 0; i < 4; ++i)
            #pragma unroll
            for (int j = 0; j < 4; ++j)
                acc[i][j] = __builtin_amdgcn_mfma_f32_16x16x32_f16(af[i], bf[j], acc[i][j], 0, 0, 0);
        __syncthreads();
    }

    #pragma unroll
    for (int i = 0; i < 4; ++i) {
        #pragma unroll
        for (int j = 0; j < 4; ++j) {
            int col = col0 + n_base + j * 16 + l15;
            #pragma unroll
            for (int r = 0; r < 4; ++r) {
                int row = row0 + m_base + i * 16 + quad * 4 + r;
                if (row < N)
                    Y[(size_t)row * 256 + col] = (_Float16)acc[i][j][r];
            }
        }
    }
}

// ================= output-side gather chain =================
template <bool OUT_F32>
__global__ __launch_bounds__(256) void gather64(
    const _Float16* __restrict__ Tin, int sin,
    const unsigned short* __restrict__ csr, const int* __restrict__ offs,
    const float* __restrict__ dinv,
    const _Float16* __restrict__ Yadd,   // stride 256, pre-offset to column block
    const float* __restrict__ cvec,      // 64 floats
    void* __restrict__ Tout, int N)
{
    int node = blockIdx.x * 32 + (threadIdx.x >> 3);
    int lane = threadIdx.x & 7;
    if (node >= N) return;
    int beg = offs[node], end = offs[node + 1];
    float acc[8] = {};
    int e = beg;
    for (; e + 3 < end; e += 4) {
        int s0 = csr[e], s1 = csr[e + 1], s2 = csr[e + 2], s3 = csr[e + 3];
        half8 v0 = *(const half8*)(Tin + (size_t)s0 * sin + lane * 8);
        half8 v1 = *(const half8*)(Tin + (size_t)s1 * sin + lane * 8);
        half8 v2 = *(const half8*)(Tin + (size_t)s2 * sin + lane * 8);
        half8 v3 = *(const half8*)(Tin + (size_t)s3 * sin + lane * 8);
        #pragma unroll
        for (int j = 0; j < 8; ++j)
            acc[j] += ((float)v0[j] + (float)v1[j]) + ((float)v2[j] + (float)v3[j]);
    }
    for (; e < end; ++e) {
        half8 v = *(const half8*)(Tin + (size_t)csr[e] * sin + lane * 8);
        #pragma unroll
        for (int j = 0; j < 8; ++j) acc[j] += (float)v[j];
    }
    float sc = dinv[node];
    half8 y = *(const half8*)(Yadd + (size_t)node * 256 + lane * 8);
    if (OUT_F32) {
        float* o = (float*)Tout + (size_t)node * 64 + lane * 8;
        float4 o0, o1;
        o0.x = acc[0] * sc + (float)y[0] + cvec[lane * 8 + 0];
        o0.y = acc[1] * sc + (float)y[1] + cvec[lane * 8 + 1];
        o0.z = acc[2] * sc + (float)y[2] + cvec[lane * 8 + 2];
        o0.w = acc[3] * sc + (float)y[3] + cvec[lane * 8 + 3];
        o1.x = acc[4] * sc + (float)y[4] + cvec[lane * 8 + 4];
        o1.y = acc[5] * sc + (float)y[5] + cvec[lane * 8 + 5];
        o1.z = acc[6] * sc + (float)y[6] + cvec[lane * 8 + 6];
        o1.w = acc[7] * sc + (float)y[7] + cvec[lane * 8 + 7];
        *(float4*)o = o0;
        *(float4*)(o + 4) = o1;
    } else {
        half8 o;
        #pragma unroll
        for (int j = 0; j < 8; ++j)
            o[j] = (_Float16)(acc[j] * sc + (float)y[j] + cvec[lane * 8 + j]);
        *(half8*)((_Float16*)Tout + (size_t)node * 64 + lane * 8) = o;
    }
}

extern "C" void kernel_launch(void* const* d_in, const int* in_sizes, int n_in,
                              void* d_out, int out_size, void* d_ws, size_t ws_size,
                              hipStream_t stream) {
    const float* x    = (const float*)d_in[0];
    const int*   esrc = (const int*)d_in[1];
    const int*   edst = (const int*)d_in[2];
    const float* W0s  = (const float*)d_in[3];
    const float* W0n  = (const float*)d_in[4];
    const float* b0   = (const float*)d_in[5];
    const float* W1s  = (const float*)d_in[6];
    const float* W1n  = (const float*)d_in[7];
    const float* b1   = (const float*)d_in[8];
    const float* W2s  = (const float*)d_in[9];
    const float* W2n  = (const float*)d_in[10];
    const float* b2   = (const float*)d_in[11];
    const float* Wfc  = (const float*)d_in[12];
    const float* bfc  = (const float*)d_in[13];
    float* out = (float*)d_out;

    // ---- workspace layout ----
    _Float16* Y   = (_Float16*)d_ws;                  // N x 256  [Y0|Y1|Y2|Y3]
    _Float16* Ta  = Y + (size_t)NN * 256;             // N x 64
    _Float16* Tb  = Ta + (size_t)NN * 64;             // N x 64
    _Float16* BT  = Tb + (size_t)NN * 64;             // 256 x 128
    float* C2     = (float*)(BT + 256 * 128);         // 515 x 256
    float* C3     = C2 + CROWS * 256;                 // 515 x 256
    float* Vf     = C3 + CROWS * 256;                 // 515 x 64
    float* dinv   = Vf + CROWS * 64;                  // N
    int* cnt      = (int*)(dinv + NN);                // N
    int* offs     = cnt + NN;                         // N+1
    int* rank     = offs + NN + 1;                    // E
    int* blockSums = rank + NE;                       // SCAN_BLOCKS
    unsigned short* csr = (unsigned short*)(blockSums + SCAN_BLOCKS);  // E

    // ---- CSR build (rank captured by hist atomic; placement atomic-free) ----
    hipMemsetAsync(cnt, 0, (size_t)NN * sizeof(int), stream);
    hist_count<<<(NE + 255) / 256, 256, 0, stream>>>(edst, cnt, rank, NE);
    scan_block_sums<<<SCAN_BLOCKS, 256, 0, stream>>>(cnt, blockSums, NN);
    scan_top<<<1, 256, 0, stream>>>(blockSums, SCAN_BLOCKS);
    scan_final<<<SCAN_BLOCKS, 256, 0, stream>>>(cnt, blockSums, offs, dinv, NN);
    csr_place2<<<(NE + 255) / 256, 256, 0, stream>>>(esrc, edst, rank, offs, csr, NE);

    // ---- weight-chain composition (fp32) ----
    const int gR = (CROWS + 63) / 64;   // 9
    gemm_compose_first<<<dim3(gR, 4), 256, 0, stream>>>(W0s, W0n, b0, W1s, W1n, b1, C2);
    gemm_compose_mid<<<dim3(gR, 4), 256, 0, stream>>>(C2, W2s, W2n, b2, C3);
    gemm_compose_last<<<dim3(gR, 1), 256, 0, stream>>>(C3, Wfc, bfc, Vf, BT);

    // ---- Y = X @ [V0|V1|V2|V3] ----
    gemm_Y<<<dim3((NN + 127) / 128, 2), 256, 0, stream>>>(x, BT, Y, NN);

    // ---- output-side propagation: out = Y0 + c1 + A(Y1 + c2 + A(Y2 + c3 + A*Y3)) ----
    const int ggrid = (NN + 31) / 32;
    gather64<false><<<ggrid, 256, 0, stream>>>(
        Y + 192, 256, csr, offs, dinv, Y + 128, Vf + (size_t)514 * 64, Ta, NN);
    gather64<false><<<ggrid, 256, 0, stream>>>(
        Ta, 64, csr, offs, dinv, Y + 64, Vf + (size_t)513 * 64, Tb, NN);
    gather64<true><<<ggrid, 256, 0, stream>>>(
        Tb, 64, csr, offs, dinv, Y, Vf + (size_t)512 * 64, out, NN);
}